// Round 4
// baseline (76.697 us; speedup 1.0000x reference)
//
#include <hip/hip_runtime.h>

// PPO loss fused pipeline for MI355X (gfx950).
// R3: k_mlp -> 256 blocks x 1024 threads (16 waves, 4 waves/SIMD, 1 block/CU).
// 256 rows/block; smH 128KB in LDS; reg-staging everywhere (no global_load_lds
// => no forced vmcnt(0) barrier drains); weight staging amortized 4x.

#define TT 65536

typedef float f32x4 __attribute__((ext_vector_type(4)));
typedef __bf16 bf16x8 __attribute__((ext_vector_type(8)));
typedef unsigned short u16x8 __attribute__((ext_vector_type(8)));

__device__ __forceinline__ unsigned short f2bf(float f) {
    unsigned int u = __float_as_uint(f);
    unsigned int r = (u + 0x7fffu + ((u >> 16) & 1u)) >> 16;
    return (unsigned short)r;
}

// branch-free tanh: 1 - 2/(e^{2x}+1)
__device__ __forceinline__ float fast_tanh(float x) {
    float e = __expf(2.0f * x);
    return fmaf(-2.0f, __builtin_amdgcn_rcpf(e + 1.0f), 1.0f);
}

// ---------------- GAE affine suffix scan ----------------
__device__ __forceinline__ void suffix_scan256(float* sC, float* sD, int i) {
    float c = sC[i], d = sD[i];
#pragma unroll
    for (int s = 1; s < 256; s <<= 1) {
        float c2 = 1.0f, d2 = 0.0f;
        if (i + s < 256) { c2 = sC[i + s]; d2 = sD[i + s]; }
        __syncthreads();
        d = d + c * d2;
        c = c * c2;
        sC[i] = c; sD[i] = d;
        __syncthreads();
    }
}

__device__ __forceinline__ void gae_cd(const float* rewards, const float* terms,
                                       const float* values, int t, float* c, float* d) {
    float nt = 1.0f - terms[t];
    float nv = (t + 1 < TT) ? values[t + 1] : 0.0f;
    *d = rewards[t] + 0.99f * nv * nt - values[t];
    *c = 0.99f * 0.95f * nt;
}

// ---------------- fused prep + gae1 ----------------
__global__ void k_prep_gae1(const float* __restrict__ W1, const float* __restrict__ W2,
                            const float* __restrict__ Wa, const float* __restrict__ Wc,
                            unsigned short* __restrict__ W1T, unsigned short* __restrict__ W2T,
                            unsigned short* __restrict__ WavT,
                            const float* __restrict__ rewards, const float* __restrict__ terms,
                            const float* __restrict__ values, float* __restrict__ aggC,
                            float* __restrict__ aggD) {
    if (blockIdx.x < 800) {
        int idx = blockIdx.x * 256 + threadIdx.x;
        if (idx < 131072) {
            int n = idx >> 9, k = idx & 511;          // W1T[n][k] = W1[k][n]
            W1T[idx] = f2bf(W1[k * 256 + n]);
        } else if (idx < 196608) {
            int i = idx - 131072;
            int n = i >> 8, k = i & 255;              // W2T[n][k] = W2[k][n]
            W2T[i] = f2bf(W2[k * 256 + n]);
        } else if (idx < 204800) {
            int i = idx - 196608;
            int r = i >> 8, k = i & 255;              // rows 0-15: Wa^T, 16: Wc^T, 17-31: 0
            float v = (r < 16) ? Wa[k * 16 + r] : ((r == 16) ? Wc[k] : 0.0f);
            WavT[i] = f2bf(v);
        }
        return;
    }
    __shared__ float sC[256], sD[256];
    int i = threadIdx.x;
    int b = blockIdx.x - 800;
    int t = b * 256 + i;
    float c, d;
    gae_cd(rewards, terms, values, t, &c, &d);
    sC[i] = c; sD[i] = d;
    __syncthreads();
    suffix_scan256(sC, sD, i);
    if (i == 0) { aggC[b] = sC[0]; aggD[b] = sD[0]; }
}

// ---------------- gae3: carry + adv/ret + per-block sum partials ----------------
__global__ void k_gae3(const float* __restrict__ rewards, const float* __restrict__ terms,
                       const float* __restrict__ values, const float* __restrict__ aggC,
                       const float* __restrict__ aggD, float* __restrict__ adv,
                       float* __restrict__ ret, float* __restrict__ sumP) {
    __shared__ float sC[256], sD[256];
    int i = threadIdx.x, b = blockIdx.x;
    sC[i] = aggC[i]; sD[i] = aggD[i];
    __syncthreads();
    suffix_scan256(sC, sD, i);
    float carry = (b < 255) ? sD[b + 1] : 0.0f;
    __syncthreads();

    int t = b * 256 + i;
    float c, d;
    gae_cd(rewards, terms, values, t, &c, &d);
    sC[i] = c; sD[i] = d;
    __syncthreads();
    suffix_scan256(sC, sD, i);
    float a = sD[i] + sC[i] * carry;
    adv[t] = a;
    ret[t] = a + values[t];
    __syncthreads();
    sC[i] = a; sD[i] = a * a;
    __syncthreads();
#pragma unroll
    for (int s = 128; s > 0; s >>= 1) {
        if (i < s) { sC[i] += sC[i + s]; sD[i] += sD[i + s]; }
        __syncthreads();
    }
    if (i == 0) { sumP[2 * b] = sC[0]; sumP[2 * b + 1] = sD[0]; }
}

// ---------------- fused MLP + heads + loss (256 rows/block, 16 waves) ----------------
// Wave grid 4mw x 4nw; wave owns rows [mw*64,+64), cols [nw*64,+64).
// 32-wide staged tiles [R][32] swizzle: 16B slot' = slot ^ ((row>>1)&3).
// smH [256][256] swizzle: elem' = elem ^ ((row&7)<<3).
__global__ __launch_bounds__(1024, 4) void k_mlp(
    const float* __restrict__ obs, const int* __restrict__ actions,
    const float* __restrict__ logprobs, const float* __restrict__ values,
    const float* __restrict__ b1, const float* __restrict__ b2,
    const float* __restrict__ ba, const float* __restrict__ bc,
    const unsigned short* __restrict__ W1T, const unsigned short* __restrict__ W2T,
    const unsigned short* __restrict__ WavT, const float* __restrict__ adv,
    const float* __restrict__ ret, const float* __restrict__ sumP,
    float* __restrict__ lossP) {
    __shared__ __align__(16) unsigned char SM[147456];
    unsigned short* smH = (unsigned short*)SM;                       // [256][256], 128KB
    unsigned short* smB2 = (unsigned short*)(SM + 131072);           // [256][32] / Wav [32][256], 16KB
    float* red = (float*)SM;

    const int tid = threadIdx.x;
    const int wid = tid >> 6;
    const int lane = tid & 63;
    const int cl = lane & 15;
    const int gg = lane >> 4;
    const int mw = wid >> 2;
    const int nw = wid & 3;
    const int bm0 = blockIdx.x * 256;

    // staging mapping (32-wide tiles): thread -> one 16B slot
    const int srow = tid >> 2;        // 0..255
    const int sslot = tid & 3;        // 0..3
    const int sdst = srow * 32 + (((sslot ^ ((srow >> 1) & 3))) << 3);   // elem index

    // B1/A double buffers live inside smH region (dead before epilogue1)
    unsigned short* smB1b[2] = {(unsigned short*)SM, (unsigned short*)(SM + 16384)};
    unsigned short* smAb[2]  = {(unsigned short*)(SM + 32768), (unsigned short*)(SM + 49152)};

    // ---- issue first-tile loads early (hide HBM latency under stats reduce) ----
    const float* aSrc = obs + (size_t)(bm0 + srow) * 512 + sslot * 8;
    float4 ar0, ar1;
    u16x8 brf;
    ar0 = *(const float4*)(aSrc);
    ar1 = *(const float4*)(aSrc + 4);
    brf = *(const u16x8*)(W1T + srow * 512 + sslot * 8);

    // ---- adv stats (folds gae4) ----
    float meanA, rstdA;
    {
        if (tid < 256) { red[tid] = sumP[2 * tid]; red[256 + tid] = sumP[2 * tid + 1]; }
        __syncthreads();
#pragma unroll
        for (int s = 128; s > 0; s >>= 1) {
            if (tid < s) { red[tid] += red[tid + s]; red[256 + tid] += red[256 + tid + s]; }
            __syncthreads();
        }
        meanA = red[0] * (1.0f / TT);
        float var = red[256] * (1.0f / TT) - meanA * meanA;
        rstdA = 1.0f / (sqrtf(fmaxf(var, 0.0f)) + 1e-8f);
        __syncthreads();
    }

    float b1v[4], b2v[4];
#pragma unroll
    for (int n = 0; n < 4; ++n) {
        int c = nw * 64 + n * 16 + cl;
        b1v[n] = b1[c];
        b2v[n] = b2[c];
    }
    const float bav = ba[cl];
    const float bc0 = bc[0];

    f32x4 acc[4][4];
#pragma unroll
    for (int m = 0; m < 4; ++m)
#pragma unroll
        for (int n = 0; n < 4; ++n) acc[m][n] = (f32x4){0.f, 0.f, 0.f, 0.f};

    auto cvtWriteA = [&](const float4& f0, const float4& f1, unsigned short* dst) {
        u16x8 cc;
        cc[0] = f2bf(f0.x); cc[1] = f2bf(f0.y); cc[2] = f2bf(f0.z); cc[3] = f2bf(f0.w);
        cc[4] = f2bf(f1.x); cc[5] = f2bf(f1.y); cc[6] = f2bf(f1.z); cc[7] = f2bf(f1.w);
        *(u16x8*)(dst + sdst) = cc;
    };

    // prologue: write tile 0
    cvtWriteA(ar0, ar1, smAb[0]);
    *(u16x8*)(smB1b[0] + sdst) = brf;
    __syncthreads();

    u16x8 b2rf;
    // ---------------- GEMM1: K=512, 16 tiles of 32 ----------------
#pragma unroll
    for (int t = 0; t < 16; ++t) {
        // issue next-tile global loads (counted vmcnt; no barrier drain needed)
        if (t < 15) {
            ar0 = *(const float4*)(aSrc + (t + 1) * 32);
            ar1 = *(const float4*)(aSrc + (t + 1) * 32 + 4);
            brf = *(const u16x8*)(W1T + srow * 512 + (t + 1) * 32 + sslot * 8);
        } else {
            b2rf = *(const u16x8*)(W2T + srow * 256 + sslot * 8);   // GEMM2 tile 0
        }
        bf16x8 av[4], bv[4];
#pragma unroll
        for (int m = 0; m < 4; ++m) {
            int ra = mw * 64 + m * 16 + cl;
            av[m] = *(const bf16x8*)&smAb[t & 1][ra * 32 + ((gg ^ ((ra >> 1) & 3)) << 3)];
        }
#pragma unroll
        for (int n = 0; n < 4; ++n) {
            int rb = nw * 64 + n * 16 + cl;
            bv[n] = *(const bf16x8*)&smB1b[t & 1][rb * 32 + ((gg ^ ((rb >> 1) & 3)) << 3)];
        }
#pragma unroll
        for (int m = 0; m < 4; ++m)
#pragma unroll
            for (int n = 0; n < 4; ++n)
                acc[m][n] = __builtin_amdgcn_mfma_f32_16x16x32_bf16(av[m], bv[n], acc[m][n], 0, 0, 0);
        if (t < 15) {
            cvtWriteA(ar0, ar1, smAb[(t + 1) & 1]);
            *(u16x8*)(smB1b[(t + 1) & 1] + sdst) = brf;
        }
        __syncthreads();
    }

    // epilogue 1: tanh -> smH (B1/A buffers dead; smH overlaps them)
#pragma unroll
    for (int m = 0; m < 4; ++m)
#pragma unroll
        for (int n = 0; n < 4; ++n)
#pragma unroll
            for (int j = 0; j < 4; ++j) {
                int r = mw * 64 + m * 16 + gg * 4 + j;
                int c = nw * 64 + n * 16 + cl;
                smH[r * 256 + (c ^ ((r & 7) << 3))] = f2bf(fast_tanh(acc[m][n][j] + b1v[n]));
                acc[m][n][j] = 0.0f;
            }
    *(u16x8*)(smB2 + sdst) = b2rf;   // GEMM2 tile 0 into B2 region (no conflict)
    __syncthreads();

    // ---------------- GEMM2: K=256, 8 tiles of 32, single-buffered B2 ----------------
    u16x8 wvrf;
#pragma unroll
    for (int t = 0; t < 8; ++t) {
        if (t < 7) b2rf = *(const u16x8*)(W2T + srow * 256 + (t + 1) * 32 + sslot * 8);
        else       wvrf = *(const u16x8*)(WavT + (tid >> 5) * 256 + (tid & 31) * 8);
        bf16x8 av[4], bv[4];
#pragma unroll
        for (int m = 0; m < 4; ++m) {
            int ra = mw * 64 + m * 16 + cl;
            av[m] = *(const bf16x8*)&smH[ra * 256 + ((t * 32 + gg * 8) ^ ((ra & 7) << 3))];
        }
#pragma unroll
        for (int n = 0; n < 4; ++n) {
            int rb = nw * 64 + n * 16 + cl;
            bv[n] = *(const bf16x8*)&smB2[rb * 32 + ((gg ^ ((rb >> 1) & 3)) << 3)];
        }
#pragma unroll
        for (int m = 0; m < 4; ++m)
#pragma unroll
            for (int n = 0; n < 4; ++n)
                acc[m][n] = __builtin_amdgcn_mfma_f32_16x16x32_bf16(av[m], bv[n], acc[m][n], 0, 0, 0);
        __syncthreads();   // B2 reads done
        if (t < 7) {
            *(u16x8*)(smB2 + sdst) = b2rf;
            __syncthreads();   // next tile visible
        }
    }

    // epilogue 2: hidden -> smH (all GEMM2 smH reads done); Wav -> smB2 region
#pragma unroll
    for (int m = 0; m < 4; ++m)
#pragma unroll
        for (int n = 0; n < 4; ++n)
#pragma unroll
            for (int j = 0; j < 4; ++j) {
                int r = mw * 64 + m * 16 + gg * 4 + j;
                int c = nw * 64 + n * 16 + cl;
                smH[r * 256 + (c ^ ((r & 7) << 3))] = f2bf(fast_tanh(acc[m][n][j] + b2v[n]));
            }
    {
        int wrow = tid >> 5, we = (tid & 31) * 8;
        *(u16x8*)(smB2 + wrow * 256 + (we ^ ((wrow & 7) << 3))) = wvrf;
    }
    __syncthreads();

    // ---------------- heads: wave wid owns rows [wid*16, +16) ----------------
    f32x4 acc_a = {0.f, 0.f, 0.f, 0.f}, acc_v = {0.f, 0.f, 0.f, 0.f};
#pragma unroll
    for (int kk = 0; kk < 8; ++kk) {
        int r = wid * 16 + cl;
        bf16x8 av = *(const bf16x8*)&smH[r * 256 + ((kk * 32 + gg * 8) ^ ((r & 7) << 3))];
        int ra2 = cl;
        bf16x8 bva = *(const bf16x8*)&smB2[ra2 * 256 + ((kk * 32 + gg * 8) ^ ((ra2 & 7) << 3))];
        int rv = 16 + cl;
        bf16x8 bvv = *(const bf16x8*)&smB2[rv * 256 + ((kk * 32 + gg * 8) ^ ((rv & 7) << 3))];
        acc_a = __builtin_amdgcn_mfma_f32_16x16x32_bf16(av, bva, acc_a, 0, 0, 0);
        acc_v = __builtin_amdgcn_mfma_f32_16x16x32_bf16(av, bvv, acc_v, 0, 0, 0);
    }

    // ---------------- per-row softmax + PPO loss ----------------
    float lsum = 0.0f;
    const int t0 = bm0 + wid * 16;
#pragma unroll
    for (int j = 0; j < 4; ++j) {
        int t = t0 + gg * 4 + j;
        float lg = acc_a[j] + bav;
        float mx = lg;
#pragma unroll
        for (int dd = 1; dd < 16; dd <<= 1) mx = fmaxf(mx, __shfl_xor(mx, dd));
        float ex = __expf(lg - mx);
        float se = ex;
#pragma unroll
        for (int dd = 1; dd < 16; dd <<= 1) se += __shfl_xor(se, dd);
        float ls = __logf(se);
        float lp = lg - mx - ls;
        float pl = __expf(lp) * lp;
        float ent = pl;
#pragma unroll
        for (int dd = 1; dd < 16; dd <<= 1) ent += __shfl_xor(ent, dd);
        ent = -ent;
        int act = actions[t];
        float newlp = __shfl(lp, (lane & 48) | act);
        float val = __shfl(acc_v[j], lane & 48) + bc0;

        float lpo = logprobs[t];
        float at = (adv[t] - meanA) * rstdA;
        float rt = ret[t];
        float vo = values[t];
        float ratio = __expf(newlp - lpo);
        float rcl = fminf(fmaxf(ratio, 0.8f), 1.2f);
        float pg = fmaxf(-at * ratio, -at * rcl);
        float vcl = vo + fminf(fmaxf(val - vo, -0.2f), 0.2f);
        float dv = val - rt, dvc = vcl - rt;
        float vl = fmaxf(dv * dv, dvc * dvc);
        if (cl == 0) lsum += pg - 0.01f * ent + 0.25f * vl;
    }
    lsum += __shfl_xor(lsum, 16);
    lsum += __shfl_xor(lsum, 32);
    __syncthreads();                 // all heads LDS reads done; smH reusable
    if (lane == 0) red[wid] = lsum;
    __syncthreads();
    if (tid == 0) {
        float s = 0.0f;
#pragma unroll
        for (int w = 0; w < 16; ++w) s += red[w];
        lossP[blockIdx.x] = s;
    }
}

__global__ void k_final(const float* __restrict__ lossP, float* __restrict__ out) {
    __shared__ float s[256];
    int i = threadIdx.x;
    s[i] = lossP[i];
    __syncthreads();
#pragma unroll
    for (int st = 128; st > 0; st >>= 1) {
        if (i < st) s[i] += s[i + st];
        __syncthreads();
    }
    if (i == 0) out[0] = s[0] * (1.0f / TT);
}

extern "C" void kernel_launch(void* const* d_in, const int* in_sizes, int n_in,
                              void* d_out, int out_size, void* d_ws, size_t ws_size,
                              hipStream_t stream) {
    const float* obs      = (const float*)d_in[0];
    const int*   actions  = (const int*)d_in[1];
    const float* logprobs = (const float*)d_in[2];
    const float* rewards  = (const float*)d_in[3];
    const float* terms    = (const float*)d_in[4];
    const float* values   = (const float*)d_in[5];
    const float* W1 = (const float*)d_in[6];
    const float* b1 = (const float*)d_in[7];
    const float* W2 = (const float*)d_in[8];
    const float* b2 = (const float*)d_in[9];
    const float* Wa = (const float*)d_in[10];
    const float* ba = (const float*)d_in[11];
    const float* Wc = (const float*)d_in[12];
    const float* bc = (const float*)d_in[13];

    char* ws = (char*)d_ws;
    unsigned short* W1T  = (unsigned short*)(ws + 0);        // 262144 B
    unsigned short* W2T  = (unsigned short*)(ws + 262144);   // 131072 B
    unsigned short* WavT = (unsigned short*)(ws + 393216);   // 16384 B
    float* advp  = (float*)(ws + 409600);                    // 262144 B
    float* retp  = (float*)(ws + 671744);                    // 262144 B
    float* aggC  = (float*)(ws + 933888);                    // 1024 B
    float* aggD  = (float*)(ws + 934912);                    // 1024 B
    float* sumP  = (float*)(ws + 936960);                    // 2048 B
    float* lossP = (float*)(ws + 939072);                    // 1024 B

    k_prep_gae1<<<1056, 256, 0, stream>>>(W1, W2, Wa, Wc, W1T, W2T, WavT,
                                          rewards, terms, values, aggC, aggD);
    k_gae3<<<256, 256, 0, stream>>>(rewards, terms, values, aggC, aggD, advp, retp, sumP);
    k_mlp<<<256, 1024, 0, stream>>>(obs, actions, logprobs, values, b1, b2, ba, bc,
                                    W1T, W2T, WavT, advp, retp, sumP, lossP);
    k_final<<<1, 256, 0, stream>>>(lossP, (float*)d_out);
}